// Round 1
// baseline (1123.351 us; speedup 1.0000x reference)
//
#include <hip/hip_runtime.h>
#include <cmath>

// ---------------- problem constants ----------------
#define E_    8
#define H_    2048
#define IH    1408      // I
#define I2    2816      // 2*I
#define SIH   2816      // SI
#define SI2   5632      // 2*SI
#define KTOP  2
#define T_    4096
#define NA    (T_*KTOP)        // 8192 routed assignments
#define BM    128
#define BN    128
#define BK    32
#define MAXR  (NA + E_*BM)     // 9216 padded gathered rows
#define LDSW  (BK + 8)         // 40: pad keeps 16B align + conflict-free frags

typedef __attribute__((ext_vector_type(8)))  short  short8;
typedef __attribute__((ext_vector_type(4)))  short  short4v;
typedef __attribute__((ext_vector_type(8)))  __bf16 bf16x8;
typedef __attribute__((ext_vector_type(4)))  float  f32x4;
typedef unsigned short bf16r;

__device__ __forceinline__ bf16r f2b(float f) {          // RNE fp32->bf16
    unsigned int u = __float_as_uint(f);
    return (bf16r)((u + 0x7FFFu + ((u >> 16) & 1u)) >> 16);
}
__device__ __forceinline__ float b2f(bf16r s) {
    return __uint_as_float(((unsigned int)s) << 16);
}

// ---------------- routing ----------------
// route layout (ints): [0..7]=cnt [16..23]=cursor [32..40]=off [64..64+MAXR)=perm
__global__ void init_route_k(int* route) {
    int i = blockIdx.x * 256 + threadIdx.x;
    if (i < 8) { route[i] = 0; route[16 + i] = 0; }
    if (i < MAXR) route[64 + i] = -1;
}
__global__ void count_k(const int* __restrict__ idx, int* route) {
    int a = blockIdx.x * 256 + threadIdx.x;
    if (a < NA) atomicAdd(&route[idx[a]], 1);
}
__global__ void scan_k(int* route) {
    if (threadIdx.x == 0 && blockIdx.x == 0) {
        int run = 0;
        for (int e = 0; e < E_; e++) {
            route[32 + e] = run;
            run += ((route[e] + BM - 1) / BM) * BM;
        }
        route[32 + E_] = run;
    }
}
__global__ void scatter_k(const int* __restrict__ idx, int* route, int* __restrict__ inv) {
    int a = blockIdx.x * 256 + threadIdx.x;
    if (a < NA) {
        int e = idx[a];
        int p = atomicAdd(&route[16 + e], 1);
        int r = route[32 + e] + p;
        route[64 + r] = a / KTOP;   // token id
        inv[a] = r;
    }
}

// ---------------- GEMM ----------------
// AMODE: 0 = fp32 A rows direct, 1 = fp32 A rows gathered via perm, 2 = bf16 A direct
// EPI:   0 = bf16 store, 1 = fp32 store
// ROUTED: per-expert B select + early exit past off[8]
template<int AMODE, int EPI, bool ROUTED>
__global__ __launch_bounds__(256)
void gemm_k(const void* __restrict__ Av, int Kd,
            const float* __restrict__ Bg, int ldb, long bstride,
            void* __restrict__ Cv, int ldc,
            const int* __restrict__ off, const int* __restrict__ perm)
{
    __shared__ bf16r As[BM][LDSW];
    __shared__ bf16r Bt[BN][LDSW];   // transposed: Bt[n][k]

    const int n0 = blockIdx.x * BN;
    const int r0 = blockIdx.y * BM;
    int e = 0;
    if (ROUTED) {
        if (r0 >= off[E_]) return;
        while (e + 1 < E_ && off[e + 1] <= r0) e++;
    }
    const float* Be = ROUTED ? (Bg + (long)e * bstride) : Bg;

    const int tid  = threadIdx.x;
    const int lane = tid & 63;
    const int wave = tid >> 6;
    const int wm   = (wave & 1) * 64;
    const int wn   = (wave >> 1) * 64;
    const int ml   = lane & 15;
    const int kg   = lane >> 4;

    // A staging coords: 2 threads per row, 16 elems each
    const int arow  = tid >> 1;
    const int ahalf = tid & 1;
    long gArow = r0 + arow;
    bool avalid = true;
    if (AMODE == 1) {
        int tok = perm[r0 + arow];
        avalid = tok >= 0;
        gArow = avalid ? tok : 0;
    }
    // B staging coords: 2 threads per col, 16 k's each
    const int bn  = tid & 127;
    const int bkh = tid >> 7;

    f32x4 acc[4][4];
    #pragma unroll
    for (int i = 0; i < 4; i++)
        #pragma unroll
        for (int j = 0; j < 4; j++)
            acc[i][j] = f32x4{0.f, 0.f, 0.f, 0.f};

    for (int k0 = 0; k0 < Kd; k0 += BK) {
        __syncthreads();
        // ---- stage A tile -> As[row][k] (bf16)
        if (AMODE <= 1) {
            const float* ap = (const float*)Av + gArow * (long)Kd + k0 + ahalf * 16;
            float4 v0 = {0,0,0,0}, v1 = {0,0,0,0}, v2 = {0,0,0,0}, v3 = {0,0,0,0};
            if (AMODE == 0 || avalid) {
                const float4* p4 = (const float4*)ap;
                v0 = p4[0]; v1 = p4[1]; v2 = p4[2]; v3 = p4[3];
            }
            short8 u0, u1;
            u0[0]=(short)f2b(v0.x); u0[1]=(short)f2b(v0.y); u0[2]=(short)f2b(v0.z); u0[3]=(short)f2b(v0.w);
            u0[4]=(short)f2b(v1.x); u0[5]=(short)f2b(v1.y); u0[6]=(short)f2b(v1.z); u0[7]=(short)f2b(v1.w);
            u1[0]=(short)f2b(v2.x); u1[1]=(short)f2b(v2.y); u1[2]=(short)f2b(v2.z); u1[3]=(short)f2b(v2.w);
            u1[4]=(short)f2b(v3.x); u1[5]=(short)f2b(v3.y); u1[6]=(short)f2b(v3.z); u1[7]=(short)f2b(v3.w);
            *(short8*)&As[arow][ahalf * 16]     = u0;
            *(short8*)&As[arow][ahalf * 16 + 8] = u1;
        } else {
            const short8* ap = (const short8*)((const bf16r*)Av + gArow * (long)Kd + k0 + ahalf * 16);
            *(short8*)&As[arow][ahalf * 16]     = ap[0];
            *(short8*)&As[arow][ahalf * 16 + 8] = ap[1];
        }
        // ---- stage B tile -> Bt[n][k] (bf16, transposed)
        {
            const float* bp = Be + (long)(k0 + bkh * 16) * ldb + (n0 + bn);
            float bv[16];
            #pragma unroll
            for (int kk = 0; kk < 16; kk++) bv[kk] = bp[(long)kk * ldb];
            short8 w0, w1;
            #pragma unroll
            for (int kk = 0; kk < 8; kk++) { w0[kk] = (short)f2b(bv[kk]); w1[kk] = (short)f2b(bv[8 + kk]); }
            *(short8*)&Bt[bn][bkh * 16]     = w0;
            *(short8*)&Bt[bn][bkh * 16 + 8] = w1;
        }
        __syncthreads();
        // ---- compute: each wave 64x64 = 4x4 MFMAs of 16x16x32
        bf16x8 af[4], bfr[4];
        #pragma unroll
        for (int i = 0; i < 4; i++)
            af[i] = *(const bf16x8*)&As[wm + i * 16 + ml][kg * 8];
        #pragma unroll
        for (int j = 0; j < 4; j++)
            bfr[j] = *(const bf16x8*)&Bt[wn + j * 16 + ml][kg * 8];
        #pragma unroll
        for (int i = 0; i < 4; i++)
            #pragma unroll
            for (int j = 0; j < 4; j++)
                acc[i][j] = __builtin_amdgcn_mfma_f32_16x16x32_bf16(af[i], bfr[j], acc[i][j], 0, 0, 0);
    }

    // ---- epilogue: D row = (lane>>4)*4 + reg, col = lane&15 (verified m89 layout)
    const int ccol = n0 + wn + ml;
    if (EPI == 0) {
        bf16r* C = (bf16r*)Cv;
        #pragma unroll
        for (int i = 0; i < 4; i++)
            #pragma unroll
            for (int rr = 0; rr < 4; rr++) {
                long row = (long)r0 + wm + i * 16 + kg * 4 + rr;
                bf16r* cp = C + row * (long)ldc + ccol;
                #pragma unroll
                for (int j = 0; j < 4; j++) cp[j * 16] = f2b(acc[i][j][rr]);
            }
    } else {
        float* C = (float*)Cv;
        #pragma unroll
        for (int i = 0; i < 4; i++)
            #pragma unroll
            for (int rr = 0; rr < 4; rr++) {
                long row = (long)r0 + wm + i * 16 + kg * 4 + rr;
                float* cp = C + row * (long)ldc + ccol;
                #pragma unroll
                for (int j = 0; j < 4; j++) cp[j * 16] = acc[i][j][rr];
            }
    }
}

// ---------------- swiglu: act[r][c] = silu(h1[r][c]) * h1[r][c+F] ----------------
__global__ void swiglu_k(const bf16r* __restrict__ h1, bf16r* __restrict__ act, int F) {
    int c4 = blockIdx.x * 256 + threadIdx.x;   // column group of 4
    int r  = blockIdx.y;
    if (c4 * 4 >= F) return;
    const bf16r* row = h1 + (long)r * (2 * F);
    short4v a = *(const short4v*)(row + c4 * 4);
    short4v b = *(const short4v*)(row + F + c4 * 4);
    short4v o;
    #pragma unroll
    for (int q = 0; q < 4; q++) {
        float av = b2f((bf16r)a[q]);
        float bv = b2f((bf16r)b[q]);
        float s  = av / (1.0f + expf(-av));
        o[q] = (short)f2b(s * bv);
    }
    *(short4v*)(act + (long)r * F + c4 * 4) = o;
}

// ---------------- combine: out += w0*contrib[r0] + w1*contrib[r1] ----------------
__global__ void combine_k(float* __restrict__ out, const bf16r* __restrict__ contrib,
                          const int* __restrict__ inv, const float* __restrict__ tw) {
    int idx = blockIdx.x * 256 + threadIdx.x;  // one per 4 output cols; total T*H/4
    int t   = idx >> 9;                        // H/4 = 512
    int c4  = idx & 511;
    int a0  = t * KTOP;
    int r0 = inv[a0], r1 = inv[a0 + 1];
    float w0 = tw[a0], w1 = tw[a0 + 1];
    short4v c0 = *(const short4v*)(contrib + (long)r0 * H_ + c4 * 4);
    short4v c1 = *(const short4v*)(contrib + (long)r1 * H_ + c4 * 4);
    float4* op = (float4*)out + idx;
    float4 o = *op;
    o.x += w0 * b2f((bf16r)c0[0]) + w1 * b2f((bf16r)c1[0]);
    o.y += w0 * b2f((bf16r)c0[1]) + w1 * b2f((bf16r)c1[1]);
    o.z += w0 * b2f((bf16r)c0[2]) + w1 * b2f((bf16r)c1[2]);
    o.w += w0 * b2f((bf16r)c0[3]) + w1 * b2f((bf16r)c1[3]);
    *op = o;
}

// ---------------- launcher ----------------
extern "C" void kernel_launch(void* const* d_in, const int* in_sizes, int n_in,
                              void* d_out, int out_size, void* d_ws, size_t ws_size,
                              hipStream_t stream)
{
    const float* x   = (const float*)d_in[0];
    const float* tw  = (const float*)d_in[1];
    const float* W1  = (const float*)d_in[2];
    const float* W2  = (const float*)d_in[3];
    const float* Ws1 = (const float*)d_in[4];
    const float* Ws2 = (const float*)d_in[5];
    const int*   tix = (const int*)d_in[6];
    float* out = (float*)d_out;

    char* ws    = (char*)d_ws;
    int*  route = (int*)ws;                       // 64 + MAXR ints
    int*  inv   = route + 64 + MAXR;              // NA ints
    bf16r* act  = (bf16r*)(ws + (1u << 20));                 // <= 9216*1408*2 = 26 MB
    bf16r* h1   = (bf16r*)(ws + (1u << 20) + (28u << 20));   // <= 9216*2816*2 = 52 MB
    bf16r* contrib = h1;                          // reuses h1 region (h1 dead by then)
    const int* off  = route + 32;
    const int* perm = route + 64;

    // routing
    init_route_k<<<(MAXR + 255) / 256, 256, 0, stream>>>(route);
    count_k<<<(NA + 255) / 256, 256, 0, stream>>>(tix, route);
    scan_k<<<1, 64, 0, stream>>>(route);
    scatter_k<<<(NA + 255) / 256, 256, 0, stream>>>(tix, route, inv);

    // shared expert: x @ Ws1 -> h1 ; swiglu ; act @ Ws2 -> out (plain store)
    gemm_k<0, 0, false><<<dim3(SI2 / BN, T_ / BM), 256, 0, stream>>>(
        x, H_, Ws1, SI2, 0, h1, SI2, nullptr, nullptr);
    swiglu_k<<<dim3((SIH / 4 + 255) / 256, T_), 256, 0, stream>>>(h1, act, SIH);
    gemm_k<2, 1, false><<<dim3(H_ / BN, T_ / BM), 256, 0, stream>>>(
        act, SIH, Ws2, H_, 0, out, H_, nullptr, nullptr);

    // routed experts: gather(x) @ W1[e] -> h1 ; swiglu ; act @ W2[e] -> contrib ; combine
    gemm_k<1, 0, true><<<dim3(I2 / BN, MAXR / BM), 256, 0, stream>>>(
        x, H_, W1, I2, (long)H_ * I2, h1, I2, off, perm);
    swiglu_k<<<dim3((IH / 4 + 255) / 256, MAXR), 256, 0, stream>>>(h1, act, IH);
    gemm_k<2, 0, true><<<dim3(H_ / BN, MAXR / BM), 256, 0, stream>>>(
        act, IH, W2, H_, (long)IH * H_, contrib, H_, off, perm);
    combine_k<<<(T_ * H_ / 4) / 256, 256, 0, stream>>>(out, contrib, inv, tw);
}

// Round 2
// 992.405 us; speedup vs baseline: 1.1319x; 1.1319x over previous
//
#include <hip/hip_runtime.h>
#include <cmath>

// ---------------- problem constants ----------------
#define E_    8
#define H_    2048
#define IH    1408      // I
#define I2    2816      // 2*I
#define SIH   2816      // SI
#define SI2   5632      // 2*SI
#define KTOP  2
#define T_    4096
#define NA    (T_*KTOP)        // 8192 routed assignments
#define BM    128
#define BN    128
#define BK    32
#define MAXR  (NA + E_*BM)     // 9216 padded gathered rows

typedef __attribute__((ext_vector_type(4)))  short  short4v;
typedef __attribute__((ext_vector_type(8)))  __bf16 bf16x8;
typedef __attribute__((ext_vector_type(4)))  float  f32x4;
typedef unsigned short bf16r;

__device__ __forceinline__ bf16r f2b(float f) {          // RNE fp32->bf16
    unsigned int u = __float_as_uint(f);
    return (bf16r)((u + 0x7FFFu + ((u >> 16) & 1u)) >> 16);
}
__device__ __forceinline__ float b2f(bf16r s) {
    return __uint_as_float(((unsigned int)s) << 16);
}

// async global->LDS, 16B per lane; lds dest must be wave-uniform base (+lane*16 by HW)
__device__ __forceinline__ void gld16(const bf16r* g, void* l) {
    __builtin_amdgcn_global_load_lds((const __attribute__((address_space(1))) void*)g,
                                     (__attribute__((address_space(3))) void*)l, 16, 0, 0);
}

// ---------------- routing ----------------
// route ints: [0..7]=cnt [16..23]=cursor [32..40]=off [64,64+MAXR)=perm ; then wrow float[MAXR]
__global__ void init_route_k(int* route) {
    int i = blockIdx.x * 256 + threadIdx.x;
    if (i < 8) { route[i] = 0; route[16 + i] = 0; }
    if (i < MAXR) { route[64 + i] = -1; route[64 + MAXR + i] = 0; }
}
__global__ void count_k(const int* __restrict__ idx, int* route) {
    int a = blockIdx.x * 256 + threadIdx.x;
    if (a < NA) atomicAdd(&route[idx[a]], 1);
}
__global__ void scan_k(int* route) {
    if (threadIdx.x == 0 && blockIdx.x == 0) {
        int run = 0;
        for (int e = 0; e < E_; e++) {
            route[32 + e] = run;
            run += ((route[e] + BM - 1) / BM) * BM;
        }
        route[32 + E_] = run;
    }
}
__global__ void scatter_k(const int* __restrict__ idx, int* route, const float* __restrict__ tw) {
    int a = blockIdx.x * 256 + threadIdx.x;
    if (a < NA) {
        int e = idx[a];
        int p = atomicAdd(&route[16 + e], 1);
        int r = route[32 + e] + p;
        route[64 + r] = a / KTOP;                              // token id
        ((float*)(route + 64 + MAXR))[r] = tw[a];              // combine weight
    }
}

// ---------------- fp32 -> bf16 flat convert (x) ----------------
__global__ void cvt_k(const float* __restrict__ in, bf16r* __restrict__ out, int n4) {
    int i = blockIdx.x * 256 + threadIdx.x;
    if (i < n4) {
        float4 v = ((const float4*)in)[i];
        short4v o;
        o[0] = (short)f2b(v.x); o[1] = (short)f2b(v.y);
        o[2] = (short)f2b(v.z); o[3] = (short)f2b(v.w);
        ((short4v*)out)[i] = o;
    }
}

// ---------------- fp32 [R][C] -> bf16 [C][R] transpose-convert ----------------
__global__ void tconv_k(const float* __restrict__ in, bf16r* __restrict__ out,
                        int R, int C, long ims, long oms) {
    __shared__ bf16r tile[64][65];
    const float* inp = in + blockIdx.z * ims;
    bf16r* outp = out + blockIdx.z * oms;
    int c0 = blockIdx.x * 64, r0 = blockIdx.y * 64;
    int tx = threadIdx.x, ty = threadIdx.y;        // 64 x 4
    #pragma unroll
    for (int j = 0; j < 16; j++) {
        int r = ty * 16 + j;
        tile[r][tx] = f2b(inp[(long)(r0 + r) * C + c0 + tx]);
    }
    __syncthreads();
    #pragma unroll
    for (int j = 0; j < 16; j++) {
        int c = ty * 16 + j;
        outp[(long)(c0 + c) * R + r0 + tx] = tile[tx][c];
    }
}

// ---------------- GEMM (m97 structure) ----------------
// A: bf16 [*][lda], rows direct or gathered via perm. Bt: bf16 [N][Kd] (pre-transposed).
// EPI: 0 = bf16 store to Cv[ldc], 1 = fp32 store, 2 = atomicAdd(out[perm[r]][col], wrow[r]*acc)
template<bool GATHER, int EPI, bool ROUTED>
__global__ __launch_bounds__(256)
void gemm_k(const bf16r* __restrict__ A, int lda, int Kd,
            const bf16r* __restrict__ Bt, long bstride,
            void* __restrict__ Cv, int ldc,
            const int* __restrict__ off, const int* __restrict__ perm,
            const float* __restrict__ wrow)
{
    __shared__ __align__(16) bf16r As[BM * BK];
    __shared__ __align__(16) bf16r Bs[BN * BK];

    const int n0 = blockIdx.x * BN;
    const int r0 = blockIdx.y * BM;
    int e = 0;
    if (ROUTED) {
        if (r0 >= off[E_]) return;
        while (e + 1 < E_ && off[e + 1] <= r0) e++;
    }
    const bf16r* Bte = ROUTED ? Bt + (long)e * bstride : Bt;

    const int tid  = threadIdx.x;
    const int lane = tid & 63;
    const int wave = tid >> 6;
    const int wm   = (wave & 1) * 64;
    const int wn   = (wave >> 1) * 64;
    const int ml   = lane & 15;
    const int kg   = lane >> 4;

    // staging: chunk c = iter*256+tid covers LDS bytes c*16; row = c>>2, kgrp = tid&3
    const int srow = tid >> 2;
    const int skg  = tid & 3;
    long ra0, ra1;
    if (GATHER) {
        int t0 = perm[r0 + srow], t1 = perm[r0 + 64 + srow];
        ra0 = (long)(t0 < 0 ? 0 : t0) * lda;
        ra1 = (long)(t1 < 0 ? 0 : t1) * lda;
    } else {
        ra0 = (long)(r0 + srow) * lda;
        ra1 = (long)(r0 + 64 + srow) * lda;
    }
    const bf16r* a0p = A + ra0 + skg * 8;
    const bf16r* a1p = A + ra1 + skg * 8;
    const bf16r* b0p = Bte + (long)(n0 + srow) * Kd + skg * 8;
    const bf16r* b1p = Bte + (long)(n0 + 64 + srow) * Kd + skg * 8;
    char* asDst = (char*)As + wave * 1024;   // + lane*16 by HW
    char* bsDst = (char*)Bs + wave * 1024;

    f32x4 acc[4][4];
    #pragma unroll
    for (int i = 0; i < 4; i++)
        #pragma unroll
        for (int j = 0; j < 4; j++)
            acc[i][j] = f32x4{0.f, 0.f, 0.f, 0.f};

    for (int k0 = 0; k0 < Kd; k0 += BK) {
        gld16(a0p + k0, asDst);
        gld16(a1p + k0, asDst + 4096);
        gld16(b0p + k0, bsDst);
        gld16(b1p + k0, bsDst + 4096);
        __syncthreads();   // compiler drains vmcnt before barrier
        bf16x8 af[4], bfr[4];
        #pragma unroll
        for (int i = 0; i < 4; i++)
            af[i] = *(const bf16x8*)&As[(wm + i * 16 + ml) * BK + kg * 8];
        #pragma unroll
        for (int j = 0; j < 4; j++)
            bfr[j] = *(const bf16x8*)&Bs[(wn + j * 16 + ml) * BK + kg * 8];
        #pragma unroll
        for (int i = 0; i < 4; i++)
            #pragma unroll
            for (int j = 0; j < 4; j++)
                acc[i][j] = __builtin_amdgcn_mfma_f32_16x16x32_bf16(af[i], bfr[j], acc[i][j], 0, 0, 0);
        __syncthreads();
    }

    // epilogue: D row = kg*4 + reg, col = lane&15 (verified m89 layout)
    const int ccol = n0 + wn + ml;
    if (EPI == 0) {
        bf16r* C = (bf16r*)Cv;
        #pragma unroll
        for (int i = 0; i < 4; i++)
            #pragma unroll
            for (int rr = 0; rr < 4; rr++) {
                long row = (long)r0 + wm + i * 16 + kg * 4 + rr;
                bf16r* cp = C + row * (long)ldc + ccol;
                #pragma unroll
                for (int j = 0; j < 4; j++) cp[j * 16] = f2b(acc[i][j][rr]);
            }
    } else if (EPI == 1) {
        float* C = (float*)Cv;
        #pragma unroll
        for (int i = 0; i < 4; i++)
            #pragma unroll
            for (int rr = 0; rr < 4; rr++) {
                long row = (long)r0 + wm + i * 16 + kg * 4 + rr;
                float* cp = C + row * (long)ldc + ccol;
                #pragma unroll
                for (int j = 0; j < 4; j++) cp[j * 16] = acc[i][j][rr];
            }
    } else {
        float* C = (float*)Cv;
        #pragma unroll
        for (int i = 0; i < 4; i++)
            #pragma unroll
            for (int rr = 0; rr < 4; rr++) {
                int r = r0 + wm + i * 16 + kg * 4 + rr;
                int tok = perm[r];
                if (tok >= 0) {
                    float w = wrow[r];
                    float* cp = C + (long)tok * ldc + ccol;
                    #pragma unroll
                    for (int j = 0; j < 4; j++) atomicAdd(&cp[j * 16], w * acc[i][j][rr]);
                }
            }
    }
}

// ---------------- swiglu in place: buf[r][c] = silu(buf[r][c]) * buf[r][c+F], row stride 2F ----------------
__global__ void swiglu_k(bf16r* __restrict__ buf, int F) {
    int c4 = blockIdx.x * 256 + threadIdx.x;
    int r  = blockIdx.y;
    if (c4 * 4 >= F) return;
    bf16r* row = buf + (long)r * (2 * F);
    short4v a = *(const short4v*)(row + c4 * 4);
    short4v b = *(const short4v*)(row + F + c4 * 4);
    short4v o;
    #pragma unroll
    for (int q = 0; q < 4; q++) {
        float av = b2f((bf16r)a[q]);
        float bv = b2f((bf16r)b[q]);
        float s  = av / (1.0f + expf(-av));
        o[q] = (short)f2b(s * bv);
    }
    *(short4v*)(row + c4 * 4) = o;
}

// ---------------- launcher ----------------
extern "C" void kernel_launch(void* const* d_in, const int* in_sizes, int n_in,
                              void* d_out, int out_size, void* d_ws, size_t ws_size,
                              hipStream_t stream)
{
    const float* x   = (const float*)d_in[0];
    const float* tw  = (const float*)d_in[1];
    const float* W1  = (const float*)d_in[2];
    const float* W2  = (const float*)d_in[3];
    const float* Ws1 = (const float*)d_in[4];
    const float* Ws2 = (const float*)d_in[5];
    const int*   tix = (const int*)d_in[6];
    float* out = (float*)d_out;

    char* ws    = (char*)d_ws;
    int*  route = (int*)ws;
    const int*   off  = route + 32;
    const int*   perm = route + 64;
    const float* wrow = (const float*)(route + 64 + MAXR);

    bf16r* xb   = (bf16r*)(ws + (1u << 20));
    bf16r* W1t  = xb   + (size_t)T_ * H_;          //  8.39 M
    bf16r* W2t  = W1t  + (size_t)E_ * I2 * H_;     // 46.14 M
    bf16r* Ws1t = W2t  + (size_t)E_ * H_ * IH;     // 23.07 M
    bf16r* Ws2t = Ws1t + (size_t)SI2 * H_;         // 11.53 M
    bf16r* h1   = Ws2t + (size_t)H_ * SIH;         //  5.77 M ; h1 itself 25.95 M
    // total ~243 MB

    // routing
    init_route_k<<<(MAXR + 255) / 256, 256, 0, stream>>>(route);
    count_k<<<(NA + 255) / 256, 256, 0, stream>>>(tix, route);
    scan_k<<<1, 64, 0, stream>>>(route);
    scatter_k<<<(NA + 255) / 256, 256, 0, stream>>>(tix, route, tw);

    // converts: x flat; weights transpose-convert to [N][K] bf16
    cvt_k<<<(T_ * H_ / 4 + 255) / 256, 256, 0, stream>>>(x, xb, T_ * H_ / 4);
    tconv_k<<<dim3(SI2 / 64, H_ / 64, 1), dim3(64, 4), 0, stream>>>(Ws1, Ws1t, H_, SI2, 0, 0);
    tconv_k<<<dim3(H_ / 64, SIH / 64, 1), dim3(64, 4), 0, stream>>>(Ws2, Ws2t, SIH, H_, 0, 0);
    tconv_k<<<dim3(I2 / 64, H_ / 64, E_), dim3(64, 4), 0, stream>>>(W1, W1t, H_, I2,
                                                                    (long)H_ * I2, (long)I2 * H_);
    tconv_k<<<dim3(H_ / 64, IH / 64, E_), dim3(64, 4), 0, stream>>>(W2, W2t, IH, H_,
                                                                    (long)IH * H_, (long)H_ * IH);

    // shared expert: xb @ Ws1t^T -> h1 [T][SI2] ; swiglu in place ; act @ Ws2t^T -> out (fp32)
    gemm_k<false, 0, false><<<dim3(SI2 / BN, T_ / BM), 256, 0, stream>>>(
        xb, H_, H_, Ws1t, 0, h1, SI2, nullptr, nullptr, nullptr);
    swiglu_k<<<dim3((SIH / 4 + 255) / 256, T_), 256, 0, stream>>>(h1, SIH);
    gemm_k<false, 1, false><<<dim3(H_ / BN, T_ / BM), 256, 0, stream>>>(
        h1, SI2, SIH, Ws2t, 0, out, H_, nullptr, nullptr, nullptr);

    // routed: gather(xb) @ W1t[e]^T -> h1 [MAXR][I2] ; swiglu ; act @ W2t[e]^T -> atomic out
    gemm_k<true, 0, true><<<dim3(I2 / BN, MAXR / BM), 256, 0, stream>>>(
        xb, H_, H_, W1t, (long)I2 * H_, h1, I2, off, perm, nullptr);
    swiglu_k<<<dim3((IH / 4 + 255) / 256, MAXR), 256, 0, stream>>>(h1, IH);
    gemm_k<false, 2, true><<<dim3(H_ / BN, MAXR / BM), 256, 0, stream>>>(
        h1, I2, IH, W2t, (long)H_ * IH, out, H_, off, perm, wrow);
}

// Round 3
// 958.778 us; speedup vs baseline: 1.1716x; 1.0351x over previous
//
#include <hip/hip_runtime.h>
#include <cmath>

// ---------------- problem constants ----------------
#define E_    8
#define H_    2048
#define IH    1408      // I
#define I2    2816      // 2*I
#define SIH   2816      // SI
#define SI2   5632      // 2*SI
#define KTOP  2
#define T_    4096
#define NA    (T_*KTOP)        // 8192 routed assignments
#define BM    128
#define BN    128
#define BK    32
#define MAXR  (NA + E_*BM)     // 9216 padded gathered rows

typedef __attribute__((ext_vector_type(4)))  short  short4v;
typedef __attribute__((ext_vector_type(8)))  __bf16 bf16x8;
typedef __attribute__((ext_vector_type(4)))  float  f32x4;
typedef unsigned short bf16r;

__device__ __forceinline__ bf16r f2b(float f) {          // RNE fp32->bf16
    unsigned int u = __float_as_uint(f);
    return (bf16r)((u + 0x7FFFu + ((u >> 16) & 1u)) >> 16);
}
__device__ __forceinline__ float b2f(bf16r s) {
    return __uint_as_float(((unsigned int)s) << 16);
}

// async global->LDS, 16B per lane; lds dest is wave-uniform base (+lane*16 by HW)
__device__ __forceinline__ void gld16(const bf16r* g, void* l) {
    __builtin_amdgcn_global_load_lds((const __attribute__((address_space(1))) void*)g,
                                     (__attribute__((address_space(3))) void*)l, 16, 0, 0);
}

// ---------------- routing: one block does count/scan/scatter ----------------
// route ints: [32..40]=off [64,64+MAXR)=perm ; then wrow float[MAXR]
__global__ void route_k(const int* __restrict__ idx, const float* __restrict__ tw,
                        int* __restrict__ route) {
    __shared__ int cnt[E_], cur[E_], offs[E_ + 1];
    int t = threadIdx.x;
    if (t < E_) { cnt[t] = 0; cur[t] = 0; }
    float* wrow = (float*)(route + 64 + MAXR);
    for (int i = t; i < MAXR; i += 256) { route[64 + i] = -1; wrow[i] = 0.f; }
    __syncthreads();
    for (int a = t; a < NA; a += 256) atomicAdd(&cnt[idx[a]], 1);
    __syncthreads();
    if (t == 0) {
        int run = 0;
        for (int e = 0; e < E_; e++) { offs[e] = run; run += ((cnt[e] + BM - 1) / BM) * BM; }
        offs[E_] = run;
    }
    __syncthreads();
    for (int a = t; a < NA; a += 256) {
        int e = idx[a];
        int p = atomicAdd(&cur[e], 1);
        int r = offs[e] + p;
        route[64 + r] = a / KTOP;
        wrow[r] = tw[a];
    }
    if (t <= E_) route[32 + t] = offs[t];
}

// ---------------- fp32 -> bf16 flat convert (x) ----------------
__global__ void cvt_k(const float* __restrict__ in, bf16r* __restrict__ out, int n4) {
    int i = blockIdx.x * 256 + threadIdx.x;
    if (i < n4) {
        float4 v = ((const float4*)in)[i];
        short4v o;
        o[0] = (short)f2b(v.x); o[1] = (short)f2b(v.y);
        o[2] = (short)f2b(v.z); o[3] = (short)f2b(v.w);
        ((short4v*)out)[i] = o;
    }
}

// ---------------- fp32 [R][C] -> bf16 [C][R] transpose-convert ----------------
__global__ void tconv_k(const float* __restrict__ in, bf16r* __restrict__ out,
                        int R, int C, long ims, long oms) {
    __shared__ bf16r tile[64][65];
    const float* inp = in + blockIdx.z * ims;
    bf16r* outp = out + blockIdx.z * oms;
    int c0 = blockIdx.x * 64, r0 = blockIdx.y * 64;
    int tx = threadIdx.x, ty = threadIdx.y;        // 64 x 4
    #pragma unroll
    for (int j = 0; j < 16; j++) {
        int r = ty * 16 + j;
        tile[r][tx] = f2b(inp[(long)(r0 + r) * C + c0 + tx]);
    }
    __syncthreads();
    #pragma unroll
    for (int j = 0; j < 16; j++) {
        int c = ty * 16 + j;
        outp[(long)(c0 + c) * R + r0 + tx] = tile[tx][c];
    }
}

// ---------------- GEMM1 + fused swiglu ----------------
// A: bf16 [*][lda] (rows gathered via perm if GATHER). Bt: bf16 [N][Kd], N = 2F (gate|up).
// Block: 128 rows x (64 gate cols f0.. + 64 up cols F+f0..).
// Wave w owns rows w*32..w*32+31, all 64 gate + 64 up cols -> in-register silu pairing.
// Writes act[row][f0+c] = silu(gate)*up, act row-major [*][F].
template<bool GATHER, bool ROUTED>
__global__ __launch_bounds__(256)
void gemm1_k(const bf16r* __restrict__ A, int lda, int Kd,
             const bf16r* __restrict__ Bt, long bstride, int F,
             bf16r* __restrict__ act,
             const int* __restrict__ off, const int* __restrict__ perm, int gM)
{
    __shared__ __align__(16) bf16r As[BM * BK];
    __shared__ __align__(16) bf16r Bs[BM * BK];   // rows 0..63 gate, 64..127 up

    const int id = blockIdx.x;          // M-fastest: same-B blocks consecutive
    const int mt = id % gM;
    const int nt = id / gM;
    const int r0 = mt * BM;
    const int f0 = nt * 64;
    int e = 0;
    if (ROUTED) {
        if (r0 >= off[E_]) return;
        while (e + 1 < E_ && off[e + 1] <= r0) e++;
    }
    const bf16r* Bte = ROUTED ? Bt + (long)e * bstride : Bt;

    const int tid  = threadIdx.x;
    const int lane = tid & 63;
    const int wave = tid >> 6;
    const int wm   = wave * 32;
    const int ml   = lane & 15;
    const int kg   = lane >> 4;

    const int srow = tid >> 2;
    const int skg  = tid & 3;
    long ra0, ra1;
    if (GATHER) {
        int t0 = perm[r0 + srow], t1 = perm[r0 + 64 + srow];
        ra0 = (long)(t0 < 0 ? 0 : t0) * lda;
        ra1 = (long)(t1 < 0 ? 0 : t1) * lda;
    } else {
        ra0 = (long)(r0 + srow) * lda;
        ra1 = (long)(r0 + 64 + srow) * lda;
    }
    const bf16r* a0p = A + ra0 + skg * 8;
    const bf16r* a1p = A + ra1 + skg * 8;
    const bf16r* b0p = Bte + (long)(f0 + srow) * Kd + skg * 8;          // gate cols
    const bf16r* b1p = Bte + (long)(F + f0 + srow) * Kd + skg * 8;      // up cols
    char* asDst = (char*)As + wave * 1024;
    char* bsDst = (char*)Bs + wave * 1024;

    f32x4 accg[2][4], accu[2][4];
    #pragma unroll
    for (int i = 0; i < 2; i++)
        #pragma unroll
        for (int j = 0; j < 4; j++) {
            accg[i][j] = f32x4{0.f, 0.f, 0.f, 0.f};
            accu[i][j] = f32x4{0.f, 0.f, 0.f, 0.f};
        }

    for (int k0 = 0; k0 < Kd; k0 += BK) {
        gld16(a0p + k0, asDst);
        gld16(a1p + k0, asDst + 4096);
        gld16(b0p + k0, bsDst);
        gld16(b1p + k0, bsDst + 4096);
        __syncthreads();
        bf16x8 af[2], bg[4], bu[4];
        #pragma unroll
        for (int i = 0; i < 2; i++)
            af[i] = *(const bf16x8*)&As[(wm + i * 16 + ml) * BK + kg * 8];
        #pragma unroll
        for (int j = 0; j < 4; j++) {
            bg[j] = *(const bf16x8*)&Bs[(j * 16 + ml) * BK + kg * 8];
            bu[j] = *(const bf16x8*)&Bs[(64 + j * 16 + ml) * BK + kg * 8];
        }
        #pragma unroll
        for (int i = 0; i < 2; i++)
            #pragma unroll
            for (int j = 0; j < 4; j++) {
                accg[i][j] = __builtin_amdgcn_mfma_f32_16x16x32_bf16(af[i], bg[j], accg[i][j], 0, 0, 0);
                accu[i][j] = __builtin_amdgcn_mfma_f32_16x16x32_bf16(af[i], bu[j], accu[i][j], 0, 0, 0);
            }
        __syncthreads();
    }

    // epilogue: D row = kg*4+reg, col = lane&15 (verified m89); pair in-register
    #pragma unroll
    for (int i = 0; i < 2; i++)
        #pragma unroll
        for (int rr = 0; rr < 4; rr++) {
            long row = (long)r0 + wm + i * 16 + kg * 4 + rr;
            bf16r* ap = act + row * (long)F + f0 + ml;
            #pragma unroll
            for (int j = 0; j < 4; j++) {
                float g = accg[i][j][rr];
                float u = accu[i][j][rr];
                float s = g / (1.0f + __expf(-g));
                ap[j * 16] = f2b(s * u);
            }
        }
}

// ---------------- GEMM2 ----------------
// A: bf16 act [*][Kd] contiguous. Bt: bf16 [N][Kd].
// EPI 1: fp32 plain store. EPI 2: atomicAdd(out[perm[r]][col], wrow[r]*acc).
template<int EPI, bool ROUTED>
__global__ __launch_bounds__(256)
void gemm2_k(const bf16r* __restrict__ A, int Kd,
             const bf16r* __restrict__ Bt, long bstride,
             float* __restrict__ Cv, int ldc,
             const int* __restrict__ off, const int* __restrict__ perm,
             const float* __restrict__ wrow, int gM)
{
    __shared__ __align__(16) bf16r As[BM * BK];
    __shared__ __align__(16) bf16r Bs[BN * BK];

    const int id = blockIdx.x;
    const int mt = id % gM;
    const int nt = id / gM;
    const int r0 = mt * BM;
    const int n0 = nt * BN;
    int e = 0;
    if (ROUTED) {
        if (r0 >= off[E_]) return;
        while (e + 1 < E_ && off[e + 1] <= r0) e++;
    }
    const bf16r* Bte = ROUTED ? Bt + (long)e * bstride : Bt;

    const int tid  = threadIdx.x;
    const int lane = tid & 63;
    const int wave = tid >> 6;
    const int wm   = (wave & 1) * 64;
    const int wn   = (wave >> 1) * 64;
    const int ml   = lane & 15;
    const int kg   = lane >> 4;

    const int srow = tid >> 2;
    const int skg  = tid & 3;
    const bf16r* a0p = A + (long)(r0 + srow) * Kd + skg * 8;
    const bf16r* a1p = A + (long)(r0 + 64 + srow) * Kd + skg * 8;
    const bf16r* b0p = Bte + (long)(n0 + srow) * Kd + skg * 8;
    const bf16r* b1p = Bte + (long)(n0 + 64 + srow) * Kd + skg * 8;
    char* asDst = (char*)As + wave * 1024;
    char* bsDst = (char*)Bs + wave * 1024;

    f32x4 acc[4][4];
    #pragma unroll
    for (int i = 0; i < 4; i++)
        #pragma unroll
        for (int j = 0; j < 4; j++)
            acc[i][j] = f32x4{0.f, 0.f, 0.f, 0.f};

    for (int k0 = 0; k0 < Kd; k0 += BK) {
        gld16(a0p + k0, asDst);
        gld16(a1p + k0, asDst + 4096);
        gld16(b0p + k0, bsDst);
        gld16(b1p + k0, bsDst + 4096);
        __syncthreads();
        bf16x8 af[4], bfr[4];
        #pragma unroll
        for (int i = 0; i < 4; i++)
            af[i] = *(const bf16x8*)&As[(wm + i * 16 + ml) * BK + kg * 8];
        #pragma unroll
        for (int j = 0; j < 4; j++)
            bfr[j] = *(const bf16x8*)&Bs[(wn + j * 16 + ml) * BK + kg * 8];
        #pragma unroll
        for (int i = 0; i < 4; i++)
            #pragma unroll
            for (int j = 0; j < 4; j++)
                acc[i][j] = __builtin_amdgcn_mfma_f32_16x16x32_bf16(af[i], bfr[j], acc[i][j], 0, 0, 0);
        __syncthreads();
    }

    const int ccol = n0 + wn + ml;
    if (EPI == 1) {
        #pragma unroll
        for (int i = 0; i < 4; i++)
            #pragma unroll
            for (int rr = 0; rr < 4; rr++) {
                long row = (long)r0 + wm + i * 16 + kg * 4 + rr;
                float* cp = Cv + row * (long)ldc + ccol;
                #pragma unroll
                for (int j = 0; j < 4; j++) cp[j * 16] = acc[i][j][rr];
            }
    } else {
        #pragma unroll
        for (int i = 0; i < 4; i++)
            #pragma unroll
            for (int rr = 0; rr < 4; rr++) {
                int r = r0 + wm + i * 16 + kg * 4 + rr;
                int tok = perm[r];
                if (tok >= 0) {
                    float w = wrow[r];
                    float* cp = Cv + (long)tok * ldc + ccol;
                    #pragma unroll
                    for (int j = 0; j < 4; j++) atomicAdd(&cp[j * 16], w * acc[i][j][rr]);
                }
            }
    }
}

// ---------------- launcher ----------------
extern "C" void kernel_launch(void* const* d_in, const int* in_sizes, int n_in,
                              void* d_out, int out_size, void* d_ws, size_t ws_size,
                              hipStream_t stream)
{
    const float* x   = (const float*)d_in[0];
    const float* tw  = (const float*)d_in[1];
    const float* W1  = (const float*)d_in[2];
    const float* W2  = (const float*)d_in[3];
    const float* Ws1 = (const float*)d_in[4];
    const float* Ws2 = (const float*)d_in[5];
    const int*   tix = (const int*)d_in[6];
    float* out = (float*)d_out;

    char* ws    = (char*)d_ws;
    int*  route = (int*)ws;
    const int*   off  = route + 32;
    const int*   perm = route + 64;
    const float* wrow = (const float*)(route + 64 + MAXR);

    bf16r* xb   = (bf16r*)(ws + (1u << 20));
    bf16r* W1t  = xb   + (size_t)T_ * H_;
    bf16r* W2t  = W1t  + (size_t)E_ * I2 * H_;
    bf16r* Ws1t = W2t  + (size_t)E_ * H_ * IH;
    bf16r* Ws2t = Ws1t + (size_t)SI2 * H_;
    bf16r* actS = Ws2t + (size_t)H_ * SIH;
    bf16r* actR = actS + (size_t)T_ * SIH;      // total ~240 MB

    // routing (single kernel)
    route_k<<<1, 256, 0, stream>>>(tix, tw, route);

    // converts: x flat; weights transpose-convert to [N][K] bf16
    cvt_k<<<(T_ * H_ / 4 + 255) / 256, 256, 0, stream>>>(x, xb, T_ * H_ / 4);
    tconv_k<<<dim3(SI2 / 64, H_ / 64, 1), dim3(64, 4), 0, stream>>>(Ws1, Ws1t, H_, SI2, 0, 0);
    tconv_k<<<dim3(H_ / 64, SIH / 64, 1), dim3(64, 4), 0, stream>>>(Ws2, Ws2t, SIH, H_, 0, 0);
    tconv_k<<<dim3(I2 / 64, H_ / 64, E_), dim3(64, 4), 0, stream>>>(W1, W1t, H_, I2,
                                                                    (long)H_ * I2, (long)I2 * H_);
    tconv_k<<<dim3(H_ / 64, IH / 64, E_), dim3(64, 4), 0, stream>>>(W2, W2t, IH, H_,
                                                                    (long)IH * H_, (long)H_ * IH);

    // shared expert: fused GEMM1+swiglu -> actS [T][SIH]; GEMM2 -> out (fp32 store)
    gemm1_k<false, false><<<(SIH / 64) * (T_ / BM), 256, 0, stream>>>(
        xb, H_, H_, Ws1t, 0, SIH, actS, nullptr, nullptr, T_ / BM);
    gemm2_k<1, false><<<(H_ / BN) * (T_ / BM), 256, 0, stream>>>(
        actS, SIH, Ws2t, 0, out, H_, nullptr, nullptr, nullptr, T_ / BM);

    // routed: fused GEMM1+swiglu (gathered rows) -> actR [MAXR][IH]; GEMM2 -> atomic out
    gemm1_k<true, true><<<(IH / 64) * (MAXR / BM), 256, 0, stream>>>(
        xb, H_, H_, W1t, (long)I2 * H_, IH, actR, off, perm, MAXR / BM);
    gemm2_k<2, true><<<(H_ / BN) * (MAXR / BM), 256, 0, stream>>>(
        actR, IH, W2t, (long)H_ * IH, out, H_, off, perm, wrow, MAXR / BM);
}